// Round 1
// baseline (366.039 us; speedup 1.0000x reference)
//
#include <hip/hip_runtime.h>
#include <stdint.h>

typedef __bf16 bf16x8 __attribute__((ext_vector_type(8)));
typedef float  f32x4  __attribute__((ext_vector_type(4)));

__device__ __forceinline__ uint16_t f2bf(float f) {
    uint32_t u = __builtin_bit_cast(uint32_t, f);
    u += 0x7FFFu + ((u >> 16) & 1u);          // round-to-nearest-even
    return (uint16_t)(u >> 16);
}

// ---------------------------------------------------------------------------
// Kernel 1: Q [16][256][32*32] f32  ->  Qt [16][32*32][256] bf16  (c innermost)
// ---------------------------------------------------------------------------
__global__ __launch_bounds__(256) void qtrans_kernel(const float* __restrict__ Q,
                                                     uint16_t* __restrict__ Qt) {
    __shared__ float T[64][65];
    int b = blockIdx.z, c0 = blockIdx.y * 64, sp0 = blockIdx.x * 64;
    int l = threadIdx.x & 63, wr = threadIdx.x >> 6;   // lane-in-64, quarter
    const float* src = Q + ((size_t)(b * 256 + c0) * 1024) + sp0;
    #pragma unroll 4
    for (int k = 0; k < 16; ++k) {
        int cl = wr + k * 4;
        T[cl][l] = src[(size_t)cl * 1024 + l];         // coalesced 256B rows
    }
    __syncthreads();
    uint16_t* dst = Qt + ((size_t)(b * 1024 + sp0) * 256) + c0;
    #pragma unroll 4
    for (int k = 0; k < 16; ++k) {
        int sp = wr + k * 4;
        dst[(size_t)sp * 256 + l] = f2bf(T[l][sp]);    // coalesced 128B rows
    }
}

// ---------------------------------------------------------------------------
// Kernel 2: per (b,d) GEMM  P[b][x(80)][d][i(32)] = sum_{j,c} S*Q  (bf16 MFMA)
//   M = x (80, only 0..64 used), N = i (32), K = (j0 outer 32, c inner 256)
//   LDS: S-tile [sx 0..63][c 0..255] bf16 (XOR-swizzled 16B chunks)  32 KB
//        Q-chunk double buffer [i][c] per j0                         32 KB
// ---------------------------------------------------------------------------
#define NW  5
#define TPB 320
__global__ __launch_bounds__(TPB, 2) void corr_kernel(const float* __restrict__ S,
                                                      const uint16_t* __restrict__ Qt,
                                                      float* __restrict__ P) {
    __shared__ __align__(16) uint16_t S_l[64 * 256];      // 32768 B
    __shared__ __align__(16) uint16_t Q_l[2][32 * 256];   // 32768 B  (total = 64 KB)

    const int d = blockIdx.x, b = blockIdx.y;
    const int tid = threadIdx.x, wave = tid >> 6, lane = tid & 63;
    const int l15 = lane & 15, l4 = lane >> 4;

    // ---- stage S[b, :, d, :] -> S_l[sx][c] (bf16, swizzled), reads coalesced
    {
        const float* sp = S + ((size_t)(b * 256) * 64 + (size_t)d) * 64;
        for (int idx = tid; idx < 8192; idx += TPB) {     // 128 c-pairs x 64 sx
            int cp = idx >> 6;
            int sx = idx & 63;
            int c  = cp * 2;
            float v0 = sp[(size_t)c * 4096 + sx];
            float v1 = sp[(size_t)(c + 1) * 4096 + sx];
            uint32_t pk = (uint32_t)f2bf(v0) | ((uint32_t)f2bf(v1) << 16);
            int chs = (c >> 3) ^ (sx & 7);                // 16B-chunk swizzle
            int el  = sx * 256 + chs * 8 + (c & 7);       // even -> 4B aligned
            *(uint32_t*)&S_l[el] = pk;
        }
    }

    // ---- Q chunk stager: Qt[b][i*32+j0][c] -> Q_l[buf][i][c] (swizzled)
    auto stageQ = [&](int j0, int bufi, int owner) {
        int sw, nst;
        if (owner < 0) { sw = wave; nst = NW; }
        else { if (wave == owner) return; sw = wave - (wave > owner ? 1 : 0); nst = NW - 1; }
        const uint16_t* qb = Qt + ((size_t)b * 1024 + (size_t)j0) * 256;
        uint16_t* dst = Q_l[bufi];
        for (int idx = sw * 64 + lane; idx < 1024; idx += nst * 64) {
            int i  = idx >> 5;                            // 0..31
            int cc = idx & 31;                            // 16B chunk 0..31
            int chs = cc ^ (i & 7);
            const uint16_t* s = qb + (size_t)i * (32 * 256) + cc * 8;
            *(bf16x8*)&dst[i * 256 + chs * 8] = *(const bf16x8*)s;
        }
    };

    f32x4 acc[5][2] = {};
    const bf16x8 zf = {};

    stageQ(0, 0, -1);
    __syncthreads();

    for (int j0 = 0; j0 < 32; ++j0) {
        const int bufi  = j0 & 1;
        const int owner = j0 % NW;
        if (wave == owner) {
            const uint16_t* Ql = Q_l[bufi];
            int  rowA[5];
            bool okl[5], ep[5];
            #pragma unroll
            for (int m = 0; m < 5; ++m) {
                int sx  = m * 16 + l15 + j0 - 16;
                rowA[m] = sx & 63;
                okl[m]  = ((unsigned)sx) < 64u;
                ep[m]   = (m * 16 + j0 < 16) || (m * 16 + j0 >= 65);
            }
            #pragma unroll
            for (int k = 0; k < 8; ++k) {
                int ci = k * 4 + l4;                      // 16B chunk index
                int qs = (ci ^ (l15 & 7)) * 8;
                bf16x8 b0 = *(const bf16x8*)&Ql[l15 * 256 + qs];
                bf16x8 b1 = *(const bf16x8*)&Ql[(16 + l15) * 256 + qs];
                #pragma unroll
                for (int m = 0; m < 5; ++m) {
                    bf16x8 a = *(const bf16x8*)&S_l[rowA[m] * 256 + ((ci ^ (rowA[m] & 7)) * 8)];
                    if (ep[m]) a = okl[m] ? a : zf;       // zero pad columns
                    acc[m][0] = __builtin_amdgcn_mfma_f32_16x16x32_bf16(a, b0, acc[m][0], 0, 0, 0);
                    acc[m][1] = __builtin_amdgcn_mfma_f32_16x16x32_bf16(a, b1, acc[m][1], 0, 0, 0);
                }
            }
        } else {
            if (j0 + 1 < 32) stageQ(j0 + 1, bufi ^ 1, owner);
        }
        __syncthreads();
    }

    // ---- merge 5 partial wave-accumulators via LDS, store P coalesced
    float* Pt = (float*)&Q_l[0][0];                       // reuse 10 KB of Q buffer
    for (int idx = tid; idx < 2560; idx += TPB) Pt[idx] = 0.f;
    __syncthreads();
    #pragma unroll
    for (int m = 0; m < 5; ++m)
        #pragma unroll
        for (int n = 0; n < 2; ++n)
            #pragma unroll
            for (int r = 0; r < 4; ++r) {
                int x  = m * 16 + l4 * 4 + r;             // C/D: row=(l>>4)*4+reg
                int iv = n * 16 + l15;                    //      col=lane&15
                atomicAdd(&Pt[x * 32 + iv], acc[m][n][r]);
            }
    __syncthreads();
    float* Pg = P + (size_t)b * (80 * 64 * 32) + (size_t)d * 32;
    for (int idx = tid; idx < 2560; idx += TPB) {
        int x = idx >> 5, iv = idx & 31;
        Pg[(size_t)x * (64 * 32) + iv] = Pt[idx];
    }
}

// ---------------------------------------------------------------------------
// Kernel 3: out[b,y,x] = sum_i P[b][x][y+i-16][i]
// ---------------------------------------------------------------------------
__global__ __launch_bounds__(128) void reduce_kernel(const float* __restrict__ P,
                                                     float* __restrict__ out) {
    __shared__ float T[64 * 32];
    int x = blockIdx.x, b = blockIdx.y;
    const float* src = P + ((size_t)(b * 80 + x)) * 2048;
    for (int idx = threadIdx.x; idx < 2048; idx += 128) T[idx] = src[idx];
    __syncthreads();
    int y = threadIdx.x;
    if (y < 65) {
        int ilo = 16 - y; if (ilo < 0) ilo = 0;
        int ihi = 80 - y; if (ihi > 32) ihi = 32;
        float s = 0.f;
        for (int i = ilo; i < ihi; ++i) s += T[(y + i - 16) * 32 + i];
        out[(size_t)b * 4225 + y * 65 + x] = s;
    }
}

// ---------------------------------------------------------------------------
// fp32 fallback (only if workspace is too small) — slow but exact
// ---------------------------------------------------------------------------
__global__ __launch_bounds__(256) void naive_kernel(const float* __restrict__ Q,
                                                    const float* __restrict__ S,
                                                    float* __restrict__ out) {
    int gid = blockIdx.x * 256 + threadIdx.x;
    if (gid >= 67600) return;
    int b = gid / 4225, r = gid % 4225, y = r / 65, x = r % 65;
    int jlo = 16 - x; if (jlo < 0) jlo = 0;
    int jhi = 80 - x; if (jhi > 32) jhi = 32;
    float acc = 0.f;
    for (int c = 0; c < 256; ++c) {
        const float* Sb = S + ((size_t)(b * 256 + c)) * 4096;
        const float* Qb = Q + ((size_t)(b * 256 + c)) * 1024;
        for (int i = 0; i < 32; ++i) {
            int dd = y + i - 16;
            if ((unsigned)dd >= 64u) continue;
            const float* Sr = Sb + dd * 64 + (x - 16);
            const float* Qr = Qb + i * 32;
            for (int j = jlo; j < jhi; ++j) acc += Sr[j] * Qr[j];
        }
    }
    out[gid] = acc;
}

extern "C" void kernel_launch(void* const* d_in, const int* in_sizes, int n_in,
                              void* d_out, int out_size, void* d_ws, size_t ws_size,
                              hipStream_t stream) {
    (void)in_sizes; (void)n_in; (void)out_size;
    const float* Q = (const float*)d_in[0];   // [16,256,32,32] f32
    const float* S = (const float*)d_in[1];   // [16,256,64,64] f32
    float* out = (float*)d_out;               // [16,1,65,65] f32

    const size_t QT_BYTES = (size_t)16 * 1024 * 256 * 2;    //  8,388,608
    const size_t P_BYTES  = (size_t)16 * 80 * 64 * 32 * 4;  // 10,485,760

    if (ws_size < QT_BYTES + P_BYTES) {
        naive_kernel<<<(67600 + 255) / 256, 256, 0, stream>>>(Q, S, out);
        return;
    }
    uint16_t* Qt = (uint16_t*)d_ws;
    float*    P  = (float*)((char*)d_ws + QT_BYTES);

    qtrans_kernel<<<dim3(16, 4, 16), 256, 0, stream>>>(Q, Qt);
    corr_kernel<<<dim3(64, 16), TPB, 0, stream>>>(S, Qt, P);
    reduce_kernel<<<dim3(65, 16), 128, 0, stream>>>(P, out);
}

// Round 2
// 177.162 us; speedup vs baseline: 2.0661x; 2.0661x over previous
//
#include <hip/hip_runtime.h>
#include <stdint.h>

typedef __bf16 bf16x8 __attribute__((ext_vector_type(8)));
typedef float  f32x4  __attribute__((ext_vector_type(4)));
typedef uint32_t u32x4 __attribute__((ext_vector_type(4)));

__device__ __forceinline__ uint16_t f2bf(float f) {
    uint32_t u = __builtin_bit_cast(uint32_t, f);
    u += 0x7FFFu + ((u >> 16) & 1u);          // round-to-nearest-even
    return (uint16_t)(u >> 16);
}

// ---------------------------------------------------------------------------
// Kernel 1: Q [b][c 256][i 32][j 32] f32 -> Qt [b][ih 2][j 32][ch 32][il 16][8] bf16
//   where c = ch*8 + t (t = elem in bf16x8), i = ih*16 + il.
//   This makes the corr kernel's B-fragment load perfectly contiguous (1 KB/instr).
// Block = (ch, b): reads 8 c-planes (32 KB), transposes via padded LDS tile.
// ---------------------------------------------------------------------------
__global__ __launch_bounds__(256) void qtrans_kernel(const float* __restrict__ Q,
                                                     uint16_t* __restrict__ Qt) {
    // T[c8 8][i 32][j 33] f32, c8-stride 1064 (= 32*33+8) so bank = 8*c8 + i + j
    __shared__ float T[8 * 1064];
    const int ch = blockIdx.x, b = blockIdx.y;
    const int tid = threadIdx.x;

    const float* src = Q + ((size_t)(b * 256 + ch * 8)) * 1024;
    #pragma unroll
    for (int it = 0; it < 32; ++it) {                  // 8192 f32, coalesced
        int r = tid + it * 256;
        int c8 = r >> 10, rem = r & 1023;
        T[c8 * 1064 + (rem >> 5) * 33 + (rem & 31)] = src[(size_t)c8 * 1024 + rem];
    }
    __syncthreads();

    uint32_t* dst = (uint32_t*)Qt;                     // write bf16 pairs
    #pragma unroll
    for (int it = 0; it < 16; ++it) {                  // 4096 pairs
        int o2 = tid + it * 256;
        int t  = (o2 & 3) * 2;
        int il = (o2 >> 2) & 15;
        int j  = (o2 >> 6) & 31;
        int ih = (o2 >> 11) & 1;
        float v0 = T[t * 1064 + (ih * 16 + il) * 33 + j];
        float v1 = T[(t + 1) * 1064 + (ih * 16 + il) * 33 + j];
        uint32_t pk = (uint32_t)f2bf(v0) | ((uint32_t)f2bf(v1) << 16);
        // u32 index = ((((b*2+ih)*32 + j)*32 + ch)*16 + il)*4 + t/2
        size_t oi = ((((size_t)(b * 2 + ih) * 32 + j) * 32 + ch) * 16 + il) * 4 + (t >> 1);
        dst[oi] = pk;
    }
}

// ---------------------------------------------------------------------------
// Kernel 2: block=(b,d); P[b][x 80][d][i 32] = sum_{j,c} S[b,c,d,x+j-16]*Q[b,c,i,j]
//   4 waves, wave w owns j0 = w, w+4, ..., w+28 (no inner barriers).
//   A (shifted S rows) from LDS (rotation-swizzled, conflict-free b128).
//   B (Q fragments) straight from global Qt — used once per block, L2-resident.
// ---------------------------------------------------------------------------
__global__ __launch_bounds__(256, 3) void corr_kernel(const float* __restrict__ S,
                                                      const uint16_t* __restrict__ Qt,
                                                      float* __restrict__ P) {
    // union: S_l [row 64][pos 32][8] bf16 (32 KB)  then  Pw [4][iv 32][x 88] f32 (44 KB)
    __shared__ __align__(16) char smem[4 * 32 * 88 * 4];
    uint16_t* S_l = (uint16_t*)smem;
    float*    Pw  = (float*)smem;

    const int d = blockIdx.x, b = blockIdx.y;
    const int tid = threadIdx.x, wave = tid >> 6, lane = tid & 63;
    const int l15 = lane & 15, l4 = lane >> 4;

    // ---- stage S[b,:,d,:] -> S_l, bf16, rotation swizzle pos=(ch&24)|((ch+row)&7)
    {
        const int sx = tid & 63, w = tid >> 6;         // thread: row sx, chunks w*8..w*8+7
        const float* sp = S + ((size_t)b * 256) * 4096 + (size_t)d * 64;
        #pragma unroll
        for (int k = 0; k < 8; ++k) {
            int ch = w * 8 + k;
            float v[8];
            #pragma unroll
            for (int cc = 0; cc < 8; ++cc)
                v[cc] = sp[(size_t)(ch * 8 + cc) * 4096 + sx];   // 256B coalesced/instr
            u32x4 pk;
            #pragma unroll
            for (int q = 0; q < 4; ++q)
                pk[q] = (uint32_t)f2bf(v[2 * q]) | ((uint32_t)f2bf(v[2 * q + 1]) << 16);
            int pos = (ch & 24) | ((ch + sx) & 7);
            *(u32x4*)&S_l[sx * 256 + pos * 8] = pk;    // 8 lanes/bank-group: optimal
        }
    }
    __syncthreads();

    f32x4 acc[5][2] = {};
    const bf16x8 zf = {};

    // per-wave j0 set: no barriers inside
    for (int jj = 0; jj < 8; ++jj) {
        const int j0 = wave + jj * 4;

        // B fragments straight from global (each 1 KB contiguous per instr)
        const uint16_t* q0 = Qt + ((size_t)(b * 2 + 0) * 32 + j0) * 4096 + l4 * 128 + l15 * 8;
        const uint16_t* q1 = Qt + ((size_t)(b * 2 + 1) * 32 + j0) * 4096 + l4 * 128 + l15 * 8;

        int  rowm[5];
        bool need[5], skip[5];
        #pragma unroll
        for (int m = 0; m < 5; ++m) {
            int base = m * 16 + j0 - 16;
            skip[m] = (base <= -16) || (base >= 64);   // whole window out of range
            need[m] = (base < 0) || (base > 48);       // partial window -> lane mask
            rowm[m] = base;
        }

        #pragma unroll
        for (int s = 0; s < 8; ++s) {
            bf16x8 b0 = *(const bf16x8*)(q0 + s * 512);
            bf16x8 b1 = *(const bf16x8*)(q1 + s * 512);
            int ch = s * 4 + l4;
            #pragma unroll
            for (int m = 0; m < 5; ++m) {
                if (skip[m]) continue;                 // wave-uniform
                int row = rowm[m] + l15;
                bool ok = (unsigned)row < 64u;
                row &= 63;
                int pos = (ch & 24) | ((ch + row) & 7);
                bf16x8 a = *(const bf16x8*)&S_l[row * 256 + pos * 8];
                if (need[m]) a = ok ? a : zf;
                acc[m][0] = __builtin_amdgcn_mfma_f32_16x16x32_bf16(a, b0, acc[m][0], 0, 0, 0);
                acc[m][1] = __builtin_amdgcn_mfma_f32_16x16x32_bf16(a, b1, acc[m][1], 0, 0, 0);
            }
        }
    }

    // ---- merge 4 wave-partials (Pw overlays S_l after barrier)
    __syncthreads();
    {
        float* pw = Pw + wave * (32 * 88);
        #pragma unroll
        for (int m = 0; m < 5; ++m)
            #pragma unroll
            for (int n = 0; n < 2; ++n)
                *(f32x4*)&pw[(n * 16 + l15) * 88 + m * 16 + l4 * 4] = acc[m][n];
    }
    __syncthreads();
    float* Pg = P + (size_t)b * (80 * 64 * 32) + (size_t)d * 32;
    for (int oidx = tid; oidx < 2560; oidx += 256) {
        int iv = oidx & 31, x = oidx >> 5;
        float s = Pw[0 * 2816 + iv * 88 + x] + Pw[1 * 2816 + iv * 88 + x]
                + Pw[2 * 2816 + iv * 88 + x] + Pw[3 * 2816 + iv * 88 + x];
        Pg[(size_t)x * 2048 + iv] = s;                 // P[b][x][d][iv]
    }
}

// ---------------------------------------------------------------------------
// Kernel 3: out[b,y,x] = sum_i P[b][x][y+i-16][i]
// ---------------------------------------------------------------------------
__global__ __launch_bounds__(128) void reduce_kernel(const float* __restrict__ P,
                                                     float* __restrict__ out) {
    __shared__ float T[64 * 32];
    int x = blockIdx.x, b = blockIdx.y;
    const float* src = P + ((size_t)(b * 80 + x)) * 2048;
    for (int idx = threadIdx.x; idx < 2048; idx += 128) T[idx] = src[idx];
    __syncthreads();
    int y = threadIdx.x;
    if (y < 65) {
        int ilo = 16 - y; if (ilo < 0) ilo = 0;
        int ihi = 80 - y; if (ihi > 32) ihi = 32;
        float s = 0.f;
        for (int i = ilo; i < ihi; ++i) s += T[(y + i - 16) * 32 + i];
        out[(size_t)b * 4225 + y * 65 + x] = s;
    }
}

// ---------------------------------------------------------------------------
// fp32 fallback (only if workspace is too small) — slow but exact
// ---------------------------------------------------------------------------
__global__ __launch_bounds__(256) void naive_kernel(const float* __restrict__ Q,
                                                    const float* __restrict__ S,
                                                    float* __restrict__ out) {
    int gid = blockIdx.x * 256 + threadIdx.x;
    if (gid >= 67600) return;
    int b = gid / 4225, r = gid % 4225, y = r / 65, x = r % 65;
    int jlo = 16 - x; if (jlo < 0) jlo = 0;
    int jhi = 80 - x; if (jhi > 32) jhi = 32;
    float acc = 0.f;
    for (int c = 0; c < 256; ++c) {
        const float* Sb = S + ((size_t)(b * 256 + c)) * 4096;
        const float* Qb = Q + ((size_t)(b * 256 + c)) * 1024;
        for (int i = 0; i < 32; ++i) {
            int dd = y + i - 16;
            if ((unsigned)dd >= 64u) continue;
            const float* Sr = Sb + dd * 64 + (x - 16);
            const float* Qr = Qb + i * 32;
            for (int j = jlo; j < jhi; ++j) acc += Sr[j] * Qr[j];
        }
    }
    out[gid] = acc;
}

extern "C" void kernel_launch(void* const* d_in, const int* in_sizes, int n_in,
                              void* d_out, int out_size, void* d_ws, size_t ws_size,
                              hipStream_t stream) {
    (void)in_sizes; (void)n_in; (void)out_size;
    const float* Q = (const float*)d_in[0];   // [16,256,32,32] f32
    const float* S = (const float*)d_in[1];   // [16,256,64,64] f32
    float* out = (float*)d_out;               // [16,1,65,65] f32

    const size_t QT_BYTES = (size_t)16 * 2 * 32 * 32 * 16 * 8 * 2;  //  8,388,608
    const size_t P_BYTES  = (size_t)16 * 80 * 64 * 32 * 4;          // 10,485,760

    if (ws_size < QT_BYTES + P_BYTES) {
        naive_kernel<<<(67600 + 255) / 256, 256, 0, stream>>>(Q, S, out);
        return;
    }
    uint16_t* Qt = (uint16_t*)d_ws;
    float*    P  = (float*)((char*)d_ws + QT_BYTES);

    qtrans_kernel<<<dim3(32, 16), 256, 0, stream>>>(Q, Qt);
    corr_kernel<<<dim3(64, 16), 256, 0, stream>>>(S, Qt, P);
    reduce_kernel<<<dim3(65, 16), 128, 0, stream>>>(P, out);
}

// Round 3
// 134.800 us; speedup vs baseline: 2.7154x; 1.3143x over previous
//
#include <hip/hip_runtime.h>
#include <stdint.h>

typedef __bf16 bf16x8 __attribute__((ext_vector_type(8)));
typedef float  f32x4  __attribute__((ext_vector_type(4)));
typedef uint32_t u32x4 __attribute__((ext_vector_type(4)));

__device__ __forceinline__ uint16_t f2bf(float f) {
    uint32_t u = __builtin_bit_cast(uint32_t, f);
    u += 0x7FFFu + ((u >> 16) & 1u);          // round-to-nearest-even
    return (uint16_t)(u >> 16);
}

// ---------------------------------------------------------------------------
// Kernel 1: Q [b][c 256][i 32][j 32] f32 -> Qt [b][ih 2][j 32][ch 32][il 16][8] bf16
//   where c = ch*8 + t, i = ih*16 + il.  Corr's B-fragment load = 1 KB contiguous.
// ---------------------------------------------------------------------------
__global__ __launch_bounds__(256) void qtrans_kernel(const float* __restrict__ Q,
                                                     uint16_t* __restrict__ Qt) {
    // T[c8 8][i 32][j 33] f32, c8-stride 1064 so bank = 8*c8 + i + j
    __shared__ float T[8 * 1064];
    const int ch = blockIdx.x, b = blockIdx.y;
    const int tid = threadIdx.x;

    const float* src = Q + ((size_t)(b * 256 + ch * 8)) * 1024;
    #pragma unroll
    for (int it = 0; it < 32; ++it) {                  // 8192 f32, coalesced
        int r = tid + it * 256;
        int c8 = r >> 10, rem = r & 1023;
        T[c8 * 1064 + (rem >> 5) * 33 + (rem & 31)] = src[(size_t)c8 * 1024 + rem];
    }
    __syncthreads();

    uint32_t* dst = (uint32_t*)Qt;                     // write bf16 pairs
    #pragma unroll
    for (int it = 0; it < 16; ++it) {                  // 4096 pairs
        int o2 = tid + it * 256;
        int t  = (o2 & 3) * 2;
        int il = (o2 >> 2) & 15;
        int j  = (o2 >> 6) & 31;
        int ih = (o2 >> 11) & 1;
        float v0 = T[t * 1064 + (ih * 16 + il) * 33 + j];
        float v1 = T[(t + 1) * 1064 + (ih * 16 + il) * 33 + j];
        uint32_t pk = (uint32_t)f2bf(v0) | ((uint32_t)f2bf(v1) << 16);
        size_t oi = ((((size_t)(b * 2 + ih) * 32 + j) * 32 + ch) * 16 + il) * 4 + (t >> 1);
        dst[oi] = pk;
    }
}

// ---------------------------------------------------------------------------
// Kernel 2: block=(b,d).  P[x][i] = sum_{j,c} S[b,c,d,x+j-16]*Q[b,c,i,j],
// then epilogue atomically adds P into out[b, y=d-i+16, x].
//   LDS S_l[ch 32][row 80] of 16B chunks; row = S-row + 16 (rows 0..15 = zeros,
//   OOB clamped to zero-row 0) -> zero-conflict b128 reads, no edge masking.
//   Wave w owns j0a = w+4jj (0..15) and j0b = j0a+16; shared A fragments:
//   base'(t) = j0a + 16t serves (m=t, j0a) and (m=t-1, j0b): 5 reads / 18 MFMA.
// ---------------------------------------------------------------------------
__global__ __launch_bounds__(256, 4) void corr_kernel(const float* __restrict__ S,
                                                      const uint16_t* __restrict__ Qt,
                                                      float* __restrict__ out) {
    __shared__ __align__(16) char smem[40960];         // 40 KB -> 4 blocks/CU
    uint16_t* S_l = (uint16_t*)smem;                   // [ch][row]: idx = ch*640 + row*8
    float*    Pw  = (float*)smem;                      // overlay: [4][iv 32][x 80]

    const int d = blockIdx.x, b = blockIdx.y;
    const int tid = threadIdx.x, wave = tid >> 6, lane = tid & 63;
    const int l15 = lane & 15, l4 = lane >> 4;

    // ---- zero-fill pad rows 0..15 for all ch (8 KB)
    {
        const u32x4 z = {};
        for (int zi = tid; zi < 512; zi += 256) {
            int ch = zi >> 4, r = zi & 15;
            *(u32x4*)&S_l[ch * 640 + r * 8] = z;
        }
    }
    // ---- stage S[b,:,d,:] -> S_l[ch][sx+16] (bf16). Writes lane-contiguous.
    {
        const int sx = tid & 63, w = tid >> 6;
        const float* sp = S + ((size_t)b * 256) * 4096 + (size_t)d * 64;
        #pragma unroll
        for (int k = 0; k < 8; ++k) {
            int ch = w * 8 + k;
            float v[8];
            #pragma unroll
            for (int cc = 0; cc < 8; ++cc)
                v[cc] = sp[(size_t)(ch * 8 + cc) * 4096 + sx];   // 256B coalesced
            u32x4 pk;
            #pragma unroll
            for (int q = 0; q < 4; ++q)
                pk[q] = (uint32_t)f2bf(v[2 * q]) | ((uint32_t)f2bf(v[2 * q + 1]) << 16);
            *(u32x4*)&S_l[ch * 640 + (sx + 16) * 8] = pk;        // contiguous 1KB/wave
        }
    }
    __syncthreads();

    f32x4 acc[5][2] = {};

    #pragma unroll
    for (int jj = 0; jj < 4; ++jj) {
        const int j0a = wave + jj * 4;                 // 0..15 ; j0b = j0a+16
        const uint16_t* qa0 = Qt + (((size_t)b * 2 + 0) * 32 + j0a) * 4096 + l4 * 128 + l15 * 8;
        const uint16_t* qa1 = Qt + (((size_t)b * 2 + 1) * 32 + j0a) * 4096 + l4 * 128 + l15 * 8;
        const uint16_t* qb0 = qa0 + 16 * 4096;
        const uint16_t* qb1 = qa1 + 16 * 4096;

        int rowt[5];
        #pragma unroll
        for (int t = 0; t < 5; ++t) {
            int rr = j0a + t * 16 + l15;               // <= 94
            rowt[t] = (rr < 80) ? rr : 0;              // OOB -> zero-row (garbage x>=65)
        }

        #pragma unroll
        for (int s = 0; s < 8; ++s) {
            bf16x8 Ba0 = *(const bf16x8*)(qa0 + s * 512);
            bf16x8 Ba1 = *(const bf16x8*)(qa1 + s * 512);
            bf16x8 Bb0 = *(const bf16x8*)(qb0 + s * 512);
            bf16x8 Bb1 = *(const bf16x8*)(qb1 + s * 512);
            const int chb = (s * 4 + l4) * 640;
            bf16x8 A[5];
            #pragma unroll
            for (int t = 0; t < 5; ++t)
                A[t] = *(const bf16x8*)&S_l[chb + rowt[t] * 8];  // conflict-free b128
            #pragma unroll
            for (int t = 0; t < 5; ++t) {
                acc[t][0] = __builtin_amdgcn_mfma_f32_16x16x32_bf16(A[t], Ba0, acc[t][0], 0, 0, 0);
                acc[t][1] = __builtin_amdgcn_mfma_f32_16x16x32_bf16(A[t], Ba1, acc[t][1], 0, 0, 0);
            }
            #pragma unroll
            for (int t = 1; t < 5; ++t) {
                acc[t - 1][0] = __builtin_amdgcn_mfma_f32_16x16x32_bf16(A[t], Bb0, acc[t - 1][0], 0, 0, 0);
                acc[t - 1][1] = __builtin_amdgcn_mfma_f32_16x16x32_bf16(A[t], Bb1, acc[t - 1][1], 0, 0, 0);
            }
        }
    }

    // ---- merge 4 wave-partials in LDS, then atomic-add into out
    __syncthreads();
    {
        float* pw = Pw + wave * 2560;                  // [iv 32][x 80]
        #pragma unroll
        for (int m = 0; m < 5; ++m)
            #pragma unroll
            for (int n = 0; n < 2; ++n)
                *(f32x4*)&pw[(n * 16 + l15) * 80 + m * 16 + l4 * 4] = acc[m][n];
    }
    __syncthreads();
    for (int e = tid; e < 65 * 32; e += 256) {
        int x = e % 65, i = e / 65;
        int y = d - i + 16;
        if ((unsigned)y < 65u) {
            float v = Pw[0 * 2560 + i * 80 + x] + Pw[1 * 2560 + i * 80 + x]
                    + Pw[2 * 2560 + i * 80 + x] + Pw[3 * 2560 + i * 80 + x];
            atomicAdd(out + ((size_t)b * 4225 + (size_t)y * 65 + x), v);
        }
    }
}

// ---------------------------------------------------------------------------
// fp32 fallback (only if workspace is too small) — slow but exact
// ---------------------------------------------------------------------------
__global__ __launch_bounds__(256) void naive_kernel(const float* __restrict__ Q,
                                                    const float* __restrict__ S,
                                                    float* __restrict__ out) {
    int gid = blockIdx.x * 256 + threadIdx.x;
    if (gid >= 67600) return;
    int b = gid / 4225, r = gid % 4225, y = r / 65, x = r % 65;
    int jlo = 16 - x; if (jlo < 0) jlo = 0;
    int jhi = 80 - x; if (jhi > 32) jhi = 32;
    float acc = 0.f;
    for (int c = 0; c < 256; ++c) {
        const float* Sb = S + ((size_t)(b * 256 + c)) * 4096;
        const float* Qb = Q + ((size_t)(b * 256 + c)) * 1024;
        for (int i = 0; i < 32; ++i) {
            int dd = y + i - 16;
            if ((unsigned)dd >= 64u) continue;
            const float* Sr = Sb + dd * 64 + (x - 16);
            const float* Qr = Qb + i * 32;
            for (int j = jlo; j < jhi; ++j) acc += Sr[j] * Qr[j];
        }
    }
    out[gid] = acc;
}

extern "C" void kernel_launch(void* const* d_in, const int* in_sizes, int n_in,
                              void* d_out, int out_size, void* d_ws, size_t ws_size,
                              hipStream_t stream) {
    (void)in_sizes; (void)n_in; (void)out_size;
    const float* Q = (const float*)d_in[0];   // [16,256,32,32] f32
    const float* S = (const float*)d_in[1];   // [16,256,64,64] f32
    float* out = (float*)d_out;               // [16,1,65,65] f32

    const size_t QT_BYTES = (size_t)16 * 2 * 32 * 32 * 16 * 8 * 2;  // 8,388,608

    if (ws_size < QT_BYTES) {
        naive_kernel<<<(67600 + 255) / 256, 256, 0, stream>>>(Q, S, out);
        return;
    }
    uint16_t* Qt = (uint16_t*)d_ws;

    hipMemsetAsync(d_out, 0, (size_t)67600 * sizeof(float), stream);
    qtrans_kernel<<<dim3(32, 16), 256, 0, stream>>>(Q, Qt);
    corr_kernel<<<dim3(64, 16), 256, 0, stream>>>(S, Qt, out);
}